// Round 1
// baseline (1879.935 us; speedup 1.0000x reference)
//
#include <hip/hip_runtime.h>

#define NI 2048
#define NB 64
#define NC 32
#define DC 16
#define DI 8

static constexpr float SQ_EPS = 1e-7f;

// One routing pass, recomputing u on the fly.
// Grid: (NI/16, 2). Block: 1024 threads = 16 waves.
// Wave w handles input capsule i = blockIdx.x*16 + w, for the 32 batches
// b in [blockIdx.y*32, +32). Lane = (c, dg): c = output capsule (0..31),
// dg = which half of the 16-dim output (0..1). W fragment (64 floats) lives
// in registers for the whole b-loop — W is read exactly twice per pass
// (once per b-half), 64 MB/pass, L3-resident after pass 1.
// MODE 0: uniform coupling c=1/32 (iteration 1, softmax of zeros).
// MODE 1: logits = dot(u, veff) where veff = NI * (v1 [+ v2]) premultiplied.
template <int MODE>
__global__ __launch_bounds__(1024) void route_pass(
    const float* __restrict__ x, const float* __restrict__ W,
    const float* __restrict__ veff, float* __restrict__ s_out)
{
    // s accumulator: [bb 0..31][c 0..31] with stride 17 floats (16 used).
    // 17 is odd -> ds_add bank = (17c + 8dg + dd) % 32: within a dg-group a
    // bijection over banks; across dg-groups exactly 2-way aliasing (free).
    __shared__ float s_lds[32 * 32 * 17];  // 68 KB

    const int tid = threadIdx.x;
    for (int k = tid; k < 32 * 32 * 17; k += 1024) s_lds[k] = 0.0f;
    __syncthreads();

    const int wave = tid >> 6;
    const int lane = tid & 63;
    const int c    = lane & 31;
    const int dg   = lane >> 5;                 // 0 or 1: d in [dg*8, dg*8+8)
    const int i    = blockIdx.x * 16 + wave;
    const int b0   = blockIdx.y * 32;

    // Load W[c][i][dg*8+dd][f] fragment into registers (64 VGPRs).
    float w[8][8];
    const float* Wp = W + (size_t)(c * NI + i) * (DC * DI) + dg * 64;
#pragma unroll
    for (int dd = 0; dd < 8; ++dd) {
        const float4 lo = *reinterpret_cast<const float4*>(Wp + dd * 8);
        const float4 hi = *reinterpret_cast<const float4*>(Wp + dd * 8 + 4);
        w[dd][0] = lo.x; w[dd][1] = lo.y; w[dd][2] = lo.z; w[dd][3] = lo.w;
        w[dd][4] = hi.x; w[dd][5] = hi.y; w[dd][6] = hi.z; w[dd][7] = hi.w;
    }

    for (int bb = 0; bb < 32; ++bb) {
        const int b = b0 + bb;
        const float* xp = x + (size_t)(b * NI + i) * DI;
        const float4 x0 = *reinterpret_cast<const float4*>(xp);
        const float4 x1 = *reinterpret_cast<const float4*>(xp + 4);

        // u[b,c,i,dg*8+dd] = sum_f x[b,i,f] * W[c,i,d,f]
        float u[8];
#pragma unroll
        for (int dd = 0; dd < 8; ++dd) {
            u[dd] = w[dd][0]*x0.x + w[dd][1]*x0.y + w[dd][2]*x0.z + w[dd][3]*x0.w
                  + w[dd][4]*x1.x + w[dd][5]*x1.y + w[dd][6]*x1.z + w[dd][7]*x1.w;
        }

        float coef;
        if (MODE == 0) {
            coef = 1.0f / 32.0f;
        } else {
            const float* vp = veff + (size_t)(b * NC + c) * DC + dg * 8;
            const float4 v0 = *reinterpret_cast<const float4*>(vp);
            const float4 v1 = *reinterpret_cast<const float4*>(vp + 4);
            // partial dot over this lane's 8 d's; xor-32 merges both halves
            float a = u[0]*v0.x + u[1]*v0.y + u[2]*v0.z + u[3]*v0.w
                    + u[4]*v1.x + u[5]*v1.y + u[6]*v1.z + u[7]*v1.w;
            a += __shfl_xor(a, 32);
            // softmax over the 32 c-lanes (masks <=16 stay within each half;
            // both halves hold identical 'a' so results agree)
            float m = a;
#pragma unroll
            for (int off = 16; off >= 1; off >>= 1)
                m = fmaxf(m, __shfl_xor(m, off));
            const float e = __expf(a - m);
            float ssum = e;
#pragma unroll
            for (int off = 16; off >= 1; off >>= 1)
                ssum += __shfl_xor(ssum, off);
            coef = e / ssum;
        }

        float* sl = &s_lds[(bb * 32 + c) * 17 + dg * 8];
#pragma unroll
        for (int dd = 0; dd < 8; ++dd)
            atomicAdd(&sl[dd], coef * u[dd]);
    }
    __syncthreads();

    // Flush block-level partial s to global (atomic across the 128 i-strips).
    {
        const int bb = tid >> 5;
        const int cc = tid & 31;
        const float* sl = &s_lds[(bb * 32 + cc) * 17];
        float* gp = s_out + (size_t)((b0 + bb) * NC + cc) * DC;
#pragma unroll
        for (int k = 0; k < DC; ++k)
            atomicAdd(&gp[k], sl[k]);
    }
}

// phase 1: veff  = NI * squash(s)        (prep for pass 2)
// phase 2: veff += NI * squash(s)        (prep for pass 3)
// phase 3: out   = squash(s)             (final output v3)
__global__ void squash_kernel(const float* __restrict__ s,
                              float* __restrict__ veff,
                              float* __restrict__ out, int phase)
{
    const int row = blockIdx.x * blockDim.x + threadIdx.x;
    if (row >= NB * NC) return;
    const float* sp = s + (size_t)row * DC;
    float v[DC];
    float sq = 0.0f;
#pragma unroll
    for (int k = 0; k < DC; ++k) { v[k] = sp[k]; sq += v[k] * v[k]; }
    const float scale = sq / ((1.0f + sq) * sqrtf(sq + SQ_EPS));
    if (phase == 3) {
        float* op = out + (size_t)row * DC;
#pragma unroll
        for (int k = 0; k < DC; ++k) op[k] = scale * v[k];
    } else {
        float* vp = veff + (size_t)row * DC;
        const float ns = scale * (float)NI;
        if (phase == 1) {
#pragma unroll
            for (int k = 0; k < DC; ++k) vp[k] = ns * v[k];
        } else {
#pragma unroll
            for (int k = 0; k < DC; ++k) vp[k] += ns * v[k];
        }
    }
}

extern "C" void kernel_launch(void* const* d_in, const int* in_sizes, int n_in,
                              void* d_out, int out_size, void* d_ws, size_t ws_size,
                              hipStream_t stream) {
    (void)in_sizes; (void)n_in; (void)out_size; (void)ws_size;
    const float* x = (const float*)d_in[0];
    const float* W = (const float*)d_in[1];

    float* s_buf = (float*)d_ws;        // 32768 floats = 128 KB in workspace
    float* veff  = (float*)d_out;       // reuse d_out as veff scratch; the
                                        // final squash (phase 3) overwrites it

    const dim3 grid(NI / 16, 2);
    const size_t s_bytes = (size_t)NB * NC * DC * sizeof(float);

    // ---- iteration 1: uniform coupling
    hipMemsetAsync(s_buf, 0, s_bytes, stream);
    route_pass<0><<<grid, 1024, 0, stream>>>(x, W, nullptr, s_buf);
    squash_kernel<<<8, 256, 0, stream>>>(s_buf, veff, nullptr, 1);

    // ---- iteration 2: logits = NI * <u, v1>
    hipMemsetAsync(s_buf, 0, s_bytes, stream);
    route_pass<1><<<grid, 1024, 0, stream>>>(x, W, veff, s_buf);
    squash_kernel<<<8, 256, 0, stream>>>(s_buf, veff, nullptr, 2);

    // ---- iteration 3: logits = NI * (<u, v1> + <u, v2>)
    hipMemsetAsync(s_buf, 0, s_bytes, stream);
    route_pass<1><<<grid, 1024, 0, stream>>>(x, W, veff, s_buf);
    squash_kernel<<<8, 256, 0, stream>>>(s_buf, nullptr, (float*)d_out, 3);
}

// Round 2
// 1149.481 us; speedup vs baseline: 1.6355x; 1.6355x over previous
//
#include <hip/hip_runtime.h>

#define NI 2048
#define NB 64
#define NC 32
#define DC 16
#define DI 8

static constexpr float SQ_EPS = 1e-7f;

// One routing pass, recomputing u on the fly.
// Grid: (NI/16, 2). Block: 1024 threads = 16 waves.
// Wave w handles input capsule i = blockIdx.x*16 + w, for the 32 batches
// b in [blockIdx.y*32, +32). Lane = (c, dg): c = output capsule (0..31),
// dg = half of the 16-dim output. W fragment (64 floats) in registers for
// the whole b-loop. Block accumulates s into LDS (ds_add), then flushes a
// PRIVATE 64 KB partial to d_ws with plain coalesced stores — no global
// atomics (R1 post-mortem: 4M contended atomics = 128 MiB RMW = 96% of pass).
// MODE 0: uniform coupling 1/32. MODE 1: logits = dot(u, veff).
template <int MODE>
__global__ __launch_bounds__(1024) void route_pass(
    const float* __restrict__ x, const float* __restrict__ W,
    const float* __restrict__ veff, float* __restrict__ partial)
{
    // [bb 0..31][c 0..31] rows, stride 17 floats (16 used) -> odd stride
    // keeps ds_add 2-way-max bank aliasing (free per m136).
    __shared__ float s_lds[32 * 32 * 17];  // 68 KB

    const int tid = threadIdx.x;
    for (int k = tid; k < 32 * 32 * 17; k += 1024) s_lds[k] = 0.0f;
    __syncthreads();

    const int wave = tid >> 6;
    const int lane = tid & 63;
    const int c    = lane & 31;
    const int dg   = lane >> 5;
    const int i    = blockIdx.x * 16 + wave;
    const int b0   = blockIdx.y * 32;

    float w[8][8];
    const float* Wp = W + (size_t)(c * NI + i) * (DC * DI) + dg * 64;
#pragma unroll
    for (int dd = 0; dd < 8; ++dd) {
        const float4 lo = *reinterpret_cast<const float4*>(Wp + dd * 8);
        const float4 hi = *reinterpret_cast<const float4*>(Wp + dd * 8 + 4);
        w[dd][0] = lo.x; w[dd][1] = lo.y; w[dd][2] = lo.z; w[dd][3] = lo.w;
        w[dd][4] = hi.x; w[dd][5] = hi.y; w[dd][6] = hi.z; w[dd][7] = hi.w;
    }

    for (int bb = 0; bb < 32; ++bb) {
        const int b = b0 + bb;
        const float* xp = x + (size_t)(b * NI + i) * DI;
        const float4 x0 = *reinterpret_cast<const float4*>(xp);
        const float4 x1 = *reinterpret_cast<const float4*>(xp + 4);

        float u[8];
#pragma unroll
        for (int dd = 0; dd < 8; ++dd) {
            u[dd] = w[dd][0]*x0.x + w[dd][1]*x0.y + w[dd][2]*x0.z + w[dd][3]*x0.w
                  + w[dd][4]*x1.x + w[dd][5]*x1.y + w[dd][6]*x1.z + w[dd][7]*x1.w;
        }

        float coef;
        if (MODE == 0) {
            coef = 1.0f / 32.0f;
        } else {
            const float* vp = veff + (size_t)(b * NC + c) * DC + dg * 8;
            const float4 v0 = *reinterpret_cast<const float4*>(vp);
            const float4 v1 = *reinterpret_cast<const float4*>(vp + 4);
            float a = u[0]*v0.x + u[1]*v0.y + u[2]*v0.z + u[3]*v0.w
                    + u[4]*v1.x + u[5]*v1.y + u[6]*v1.z + u[7]*v1.w;
            a += __shfl_xor(a, 32);                 // merge dg halves
            float m = a;
#pragma unroll
            for (int off = 16; off >= 1; off >>= 1)  // softmax over 32 c-lanes
                m = fmaxf(m, __shfl_xor(m, off));
            const float e = __expf(a - m);
            float ssum = e;
#pragma unroll
            for (int off = 16; off >= 1; off >>= 1)
                ssum += __shfl_xor(ssum, off);
            coef = e / ssum;
        }

        float* sl = &s_lds[(bb * 32 + c) * 17 + dg * 8];
#pragma unroll
        for (int dd = 0; dd < 8; ++dd)
            atomicAdd(&sl[dd], coef * u[dd]);
    }
    __syncthreads();

    // Flush this block's 64 KB partial with plain coalesced stores.
    // partial[p][row 0..1023][d 0..15], p = by*128 + bx.
    {
        float* gp = partial +
            (size_t)(blockIdx.y * gridDim.x + blockIdx.x) * (32 * 32 * DC);
#pragma unroll
        for (int k = 0; k < 16; ++k) {
            const int f   = k * 1024 + tid;      // flat [row*16 + d]
            const int row = f >> 4;
            const int d   = f & 15;
            gp[f] = s_lds[row * 17 + d];
        }
    }
}

// Fused 128-way partial reduction + squash.
// Grid 128 x 256 threads: gid -> (b = gid>>9, c = (gid>>4)&31, d = gid&15).
// phase 1: veff  = NI * squash(s);  phase 2: veff += NI * squash(s);
// phase 3: out   = squash(s).
__global__ __launch_bounds__(256) void reduce_squash(
    const float* __restrict__ partial, float* __restrict__ veff,
    float* __restrict__ out, int phase)
{
    const int gid = blockIdx.x * 256 + threadIdx.x;   // 0..32767
    const int b   = gid >> 9;
    const int by  = b >> 5;
    const int bb  = b & 31;
    const int c   = (gid >> 4) & 31;
    const int d   = gid & 15;

    const float* pp = partial + (size_t)(by * 128) * (32 * 32 * DC)
                    + (bb * 32 + c) * DC + d;
    float v = 0.0f;
#pragma unroll 4
    for (int bx = 0; bx < 128; ++bx)
        v += pp[(size_t)bx * (32 * 32 * DC)];

    // |s|^2 across the 16 d-lanes (d = low 4 bits of lane id)
    float sq = v * v;
#pragma unroll
    for (int off = 8; off >= 1; off >>= 1)
        sq += __shfl_xor(sq, off);
    const float scale = sq / ((1.0f + sq) * sqrtf(sq + SQ_EPS));

    const int row = b * NC + c;
    if (phase == 3) {
        out[row * DC + d] = scale * v;
    } else if (phase == 1) {
        veff[row * DC + d] = scale * (float)NI * v;
    } else {
        veff[row * DC + d] += scale * (float)NI * v;
    }
}

extern "C" void kernel_launch(void* const* d_in, const int* in_sizes, int n_in,
                              void* d_out, int out_size, void* d_ws, size_t ws_size,
                              hipStream_t stream) {
    (void)in_sizes; (void)n_in; (void)out_size; (void)ws_size;
    const float* x = (const float*)d_in[0];
    const float* W = (const float*)d_in[1];

    float* partial = (float*)d_ws;      // 256 blocks x 64 KB = 16 MiB
    float* veff    = (float*)d_out;     // scratch; phase-3 squash overwrites

    const dim3 grid(NI / 16, 2);

    // ---- iteration 1: uniform coupling
    route_pass<0><<<grid, 1024, 0, stream>>>(x, W, nullptr, partial);
    reduce_squash<<<128, 256, 0, stream>>>(partial, veff, nullptr, 1);

    // ---- iteration 2: logits = NI * <u, v1>
    route_pass<1><<<grid, 1024, 0, stream>>>(x, W, veff, partial);
    reduce_squash<<<128, 256, 0, stream>>>(partial, veff, nullptr, 2);

    // ---- iteration 3: logits = NI * (<u, v1> + <u, v2>)
    route_pass<1><<<grid, 1024, 0, stream>>>(x, W, veff, partial);
    reduce_squash<<<128, 256, 0, stream>>>(partial, nullptr, (float*)d_out, 3);
}